// Round 10
// baseline (238.422 us; speedup 1.0000x reference)
//
#include <hip/hip_runtime.h>
#include <math.h>

typedef unsigned short u16;
typedef unsigned int u32;
typedef __attribute__((ext_vector_type(8))) short short8;
typedef __attribute__((ext_vector_type(8))) u16 ushort8_t;
typedef __attribute__((ext_vector_type(4))) u16 ushort4_t;
typedef __attribute__((ext_vector_type(2))) u32 uint2_t;
typedef __attribute__((ext_vector_type(4))) float floatx4;

#define DEV static __device__ __forceinline__

DEV u16 f2b(float f) {
    union { float f; u32 u; } v; v.f = f;
    u32 u = v.u;
    return (u16)((u + 0x7fffu + ((u >> 16) & 1u)) >> 16);
}
DEV float b2f(u16 h) {
    union { u32 u; float f; } v; v.u = ((u32)h) << 16;
    return v.f;
}
DEV u32 cvt_pk(float lo, float hi) {
    u32 r;
    asm("v_cvt_pk_bf16_f32 %0, %1, %2" : "=v"(r) : "v"(lo), "v"(hi));
    return r;
}
DEV float gelu_f(float x) {
    return 0.5f * x * (1.f + erff(x * 0.70710678118654752f));
}

// ---------------- fused weight-cvt + LayerNorm1 + dist-e table ----------------
// blocks 0..3071: f32->bf16 weight cvt. 3072..3615: LN1 rows. 3616..5663: dist-e.
__global__ __launch_bounds__(256) void cvt_ln(
    const float* __restrict__ wq, const float* __restrict__ wk,
    const float* __restrict__ wv, const float* __restrict__ wo,
    const float* __restrict__ w1, const float* __restrict__ w2,
    u16* __restrict__ oq, u16* __restrict__ ok, u16* __restrict__ ov,
    u16* __restrict__ oo, u16* __restrict__ o1, u16* __restrict__ o2,
    const float* __restrict__ hidden, const float* __restrict__ ctx,
    const float* __restrict__ g, const float* __restrict__ bta,
    u16* __restrict__ dst,
    const float* __restrict__ pos, u16* __restrict__ ebt)
{
    if (blockIdx.x < 3072) {
        long i = ((long)blockIdx.x * 256 + threadIdx.x) * 4;
        const float* s; u16* d; long off;
        if (i < 1048576) {
            int seg = (int)(i >> 18);
            off = i & 262143;
            s = seg == 0 ? wq : seg == 1 ? wk : seg == 2 ? wv : wo;
            d = seg == 0 ? oq : seg == 1 ? ok : seg == 2 ? ov : oo;
        } else if (i < 2097152) {
            off = i - 1048576; s = w1; d = o1;
        } else {
            off = i - 2097152; s = w2; d = o2;
        }
        floatx4 v = *(const floatx4*)(s + off);
        ushort4_t r;
        r[0] = f2b(v[0]); r[1] = f2b(v[1]); r[2] = f2b(v[2]); r[3] = f2b(v[3]);
        *(ushort4_t*)(d + off) = r;
        return;
    }
    if (blockIdx.x >= 3616) {
        // distance-affinity table: e = exp(-||pi-pj||^2/(2 ls^2)) as bf16
        const float inv2ls2 = 10.330578512396695f;
        int t = blockIdx.x - 3616;          // 0..2047
        int b = t >> 10, i = t & 1023;      // one row per block
        int j0 = threadIdx.x * 4;
        float px = pos[((long)b * 1024 + i) * 2];
        float py = pos[((long)b * 1024 + i) * 2 + 1];
        floatx4 a = *(const floatx4*)(pos + (long)b * 2048 + j0 * 2);
        floatx4 c = *(const floatx4*)(pos + (long)b * 2048 + j0 * 2 + 4);
        float e[4];
        {
            float dx = px - a[0], dy = py - a[1];
            e[0] = __expf(-(dx * dx + dy * dy) * inv2ls2);
            dx = px - a[2]; dy = py - a[3];
            e[1] = __expf(-(dx * dx + dy * dy) * inv2ls2);
            dx = px - c[0]; dy = py - c[1];
            e[2] = __expf(-(dx * dx + dy * dy) * inv2ls2);
            dx = px - c[2]; dy = py - c[3];
            e[3] = __expf(-(dx * dx + dy * dy) * inv2ls2);
        }
        ushort4_t r;
        r[0] = f2b(e[0]); r[1] = f2b(e[1]); r[2] = f2b(e[2]); r[3] = f2b(e[3]);
        *(ushort4_t*)(ebt + ((long)(b * 1024 + i)) * 1024 + j0) = r;
        return;
    }
    int wid = threadIdx.x >> 6, lane = threadIdx.x & 63;
    int row = (blockIdx.x - 3072) * 4 + wid;
    if (row >= 2176) return;
    int bi = row / 1088, loc = row % 1088;
    const float* src = (loc < 1024) ? hidden + ((long)(bi * 1024 + loc)) * 512
                                    : ctx + ((long)(bi * 64 + (loc - 1024))) * 512;
    const floatx4* p = (const floatx4*)(src + lane * 8);
    floatx4 a = p[0], b4 = p[1];
    float x[8];
    x[0] = a[0]; x[1] = a[1]; x[2] = a[2]; x[3] = a[3];
    x[4] = b4[0]; x[5] = b4[1]; x[6] = b4[2]; x[7] = b4[3];
    float s = 0.f, sq = 0.f;
#pragma unroll
    for (int j = 0; j < 8; j++) { s += x[j]; sq += x[j] * x[j]; }
#pragma unroll
    for (int m = 1; m < 64; m <<= 1) {
        s += __shfl_xor(s, m, 64);
        sq += __shfl_xor(sq, m, 64);
    }
    float mean = s * (1.f / 512.f);
    float var = sq * (1.f / 512.f) - mean * mean;
    float rstd = rsqrtf(var + 1e-5f);
    const floatx4* gp = (const floatx4*)(g + lane * 8);
    const floatx4* bp = (const floatx4*)(bta + lane * 8);
    floatx4 g0 = gp[0], g1 = gp[1], bb0 = bp[0], bb1 = bp[1];
    float gg[8], bbv[8];
    gg[0] = g0[0]; gg[1] = g0[1]; gg[2] = g0[2]; gg[3] = g0[3];
    gg[4] = g1[0]; gg[5] = g1[1]; gg[6] = g1[2]; gg[7] = g1[3];
    bbv[0] = bb0[0]; bbv[1] = bb0[1]; bbv[2] = bb0[2]; bbv[3] = bb0[3];
    bbv[4] = bb1[0]; bbv[5] = bb1[1]; bbv[6] = bb1[2]; bbv[7] = bb1[3];
    ushort8_t o;
#pragma unroll
    for (int j = 0; j < 8; j++) o[j] = f2b((x[j] - mean) * rstd * gg[j] + bbv[j]);
    *(ushort8_t*)(dst + (long)row * 512 + lane * 8) = o;
}

// ---------------- GEMM 128x128 tile (high MFMA density) ----------------
// OMODE 1: outb0 bf16 [M][N] (+gelu if ACT). OMODE 3: QKV scatter.
template<int ACT, int OMODE>
__global__ __launch_bounds__(256) void gemm_big(
    const u16* __restrict__ A, const u16* __restrict__ Bw,
    const float* __restrict__ bias0, const float* __restrict__ bias1,
    const float* __restrict__ bias2,
    u16* __restrict__ outb0, u16* __restrict__ outb1, u16* __restrict__ outb2,
    int M, int N, int K)
{
    __shared__ u16 As[128 * 72];
    __shared__ u16 Bs[128 * 72];
    int tid = threadIdx.x;
    int wid = tid >> 6, lane = tid & 63;
    int l16 = lane & 15, lq = lane >> 4;
    int m0 = blockIdx.y * 128, n0 = blockIdx.x * 128;
    int wm = (wid >> 1) * 64, wn = (wid & 1) * 64;
    int srow = tid >> 3;          // 0..31
    int scol = (tid & 7) * 8;     // 0..56
    floatx4 acc[4][4] = {};
    const u16* Ap = A + (long)(m0 + srow) * K + scol;
    const u16* Bp = Bw + (long)(n0 + srow) * K + scol;
    ushort8_t pa[4], pb[4];
#pragma unroll
    for (int p = 0; p < 4; p++) {
        pa[p] = *(const ushort8_t*)(Ap + (long)p * 32 * K);
        pb[p] = *(const ushort8_t*)(Bp + (long)p * 32 * K);
    }
    for (int k0 = 0; k0 < K; k0 += 64) {
#pragma unroll
        for (int p = 0; p < 4; p++) {
            *(ushort8_t*)(As + (p * 32 + srow) * 72 + scol) = pa[p];
            *(ushort8_t*)(Bs + (p * 32 + srow) * 72 + scol) = pb[p];
        }
        __syncthreads();
        int k1 = k0 + 64;
        if (k1 < K) {
#pragma unroll
            for (int p = 0; p < 4; p++) {
                pa[p] = *(const ushort8_t*)(Ap + (long)p * 32 * K + k1);
                pb[p] = *(const ushort8_t*)(Bp + (long)p * 32 * K + k1);
            }
        }
#pragma unroll
        for (int s = 0; s < 2; s++) {
            short8 af[4], bfr[4];
#pragma unroll
            for (int i = 0; i < 4; i++)
                af[i] = *(const short8*)(As + (wm + i * 16 + l16) * 72 + s * 32 + lq * 8);
#pragma unroll
            for (int j = 0; j < 4; j++)
                bfr[j] = *(const short8*)(Bs + (wn + j * 16 + l16) * 72 + s * 32 + lq * 8);
#pragma unroll
            for (int i = 0; i < 4; i++)
#pragma unroll
                for (int j = 0; j < 4; j++)
                    acc[i][j] = __builtin_amdgcn_mfma_f32_16x16x32_bf16(
                        af[i], bfr[j], acc[i][j], 0, 0, 0);
        }
        __syncthreads();
    }
    const float rs = 0.17677669529663687f;  // 1/sqrt(32)
#pragma unroll
    for (int i = 0; i < 4; i++) {
#pragma unroll
        for (int j = 0; j < 4; j++) {
            int gmb = m0 + wm + i * 16 + lq * 4;
            int gn = n0 + wn + j * 16 + l16;
#pragma unroll
            for (int r = 0; r < 4; r++) {
                int gm = gmb + r;
                float v = acc[i][j][r];
                if (OMODE == 1) {
                    v += bias0[gn];
                    if (ACT == 1) v = gelu_f(v);
                    outb0[(long)gm * N + gn] = f2b(v);
                } else {
                    if (gn < 512) {
                        outb0[(long)gm * 512 + gn] = f2b((v + bias0[gn]) * rs);
                    } else if (gn < 1024) {
                        outb1[(long)gm * 512 + gn - 512] = f2b(v + bias1[gn - 512]);
                    } else {
                        int bi = gm / 1088, tok = gm % 1088;
                        int col = gn - 1024;
                        outb2[((long)((bi * 16 + (col >> 5)) * 32 + (col & 31))) * 1088 + tok]
                            = f2b(v + bias2[col]);
                    }
                }
            }
        }
    }
}

// ---------------- GEMM 64x128 split-K ----------------
// OMODE 4: f32 partial outf[(z*M+gm)*N+gn]. OMODE 5: atomicAdd outf[gm*N+gn].
template<int OMODE>
__global__ __launch_bounds__(256) void gemm_sk(
    const u16* __restrict__ A, const u16* __restrict__ Bw,
    float* __restrict__ outf, int M, int N, int K, int ksp)
{
    __shared__ u16 As[64 * 72];
    __shared__ u16 Bs[128 * 72];
    int tid = threadIdx.x;
    int wid = tid >> 6, lane = tid & 63;
    int l16 = lane & 15, lq = lane >> 4;
    int m0 = blockIdx.y * 64, n0 = blockIdx.x * 128;
    int wm = (wid >> 1) * 32, wn = (wid & 1) * 64;
    int srow = tid >> 3;
    int scol = (tid & 7) * 8;
    int kb0 = blockIdx.z * ksp;
    int kend = kb0 + ksp;
    floatx4 acc[2][4] = {};
    const u16* Ap = A + (long)(m0 + srow) * K + scol;
    const u16* Bp = Bw + (long)(n0 + srow) * K + scol;
    ushort8_t pa[2], pb[4];
#pragma unroll
    for (int p = 0; p < 2; p++)
        pa[p] = *(const ushort8_t*)(Ap + (long)p * 32 * K + kb0);
#pragma unroll
    for (int p = 0; p < 4; p++)
        pb[p] = *(const ushort8_t*)(Bp + (long)p * 32 * K + kb0);
    for (int k0 = kb0; k0 < kend; k0 += 64) {
#pragma unroll
        for (int p = 0; p < 2; p++)
            *(ushort8_t*)(As + (p * 32 + srow) * 72 + scol) = pa[p];
#pragma unroll
        for (int p = 0; p < 4; p++)
            *(ushort8_t*)(Bs + (p * 32 + srow) * 72 + scol) = pb[p];
        __syncthreads();
        int k1 = k0 + 64;
        if (k1 < kend) {
#pragma unroll
            for (int p = 0; p < 2; p++)
                pa[p] = *(const ushort8_t*)(Ap + (long)p * 32 * K + k1);
#pragma unroll
            for (int p = 0; p < 4; p++)
                pb[p] = *(const ushort8_t*)(Bp + (long)p * 32 * K + k1);
        }
#pragma unroll
        for (int s = 0; s < 2; s++) {
            short8 af[2], bfr[4];
#pragma unroll
            for (int i = 0; i < 2; i++)
                af[i] = *(const short8*)(As + (wm + i * 16 + l16) * 72 + s * 32 + lq * 8);
#pragma unroll
            for (int j = 0; j < 4; j++)
                bfr[j] = *(const short8*)(Bs + (wn + j * 16 + l16) * 72 + s * 32 + lq * 8);
#pragma unroll
            for (int i = 0; i < 2; i++)
#pragma unroll
                for (int j = 0; j < 4; j++)
                    acc[i][j] = __builtin_amdgcn_mfma_f32_16x16x32_bf16(
                        af[i], bfr[j], acc[i][j], 0, 0, 0);
        }
        __syncthreads();
    }
#pragma unroll
    for (int i = 0; i < 2; i++) {
#pragma unroll
        for (int j = 0; j < 4; j++) {
            int gmb = m0 + wm + i * 16 + lq * 4;
            int gn = n0 + wn + j * 16 + l16;
#pragma unroll
            for (int r = 0; r < 4; r++) {
                int gm = gmb + r;
                float v = acc[i][j][r];
                if (OMODE == 4) {
                    outf[((long)blockIdx.z * M + gm) * N + gn] = v;
                } else {
                    atomicAdd(outf + (long)gm * N + gn, v);
                }
            }
        }
    }
}

// ---------------- fused flash attention (no-max, KV-split x2, table bias) ----
// grid (16 qtiles, 16 heads, 2b*2split), block 256 (4 waves x 16 query rows)
__global__ __launch_bounds__(256) void attn_kernel(
    const u16* __restrict__ qb, const u16* __restrict__ kb,
    const u16* __restrict__ vt, const float* __restrict__ adj,
    const float* __restrict__ ehc, const u16* __restrict__ ebt,
    float* __restrict__ o_part, float* __restrict__ l_part)
{
    __shared__ u16 P[4][1152];            // per-wave P tile (16 x 72)
    __shared__ u16 ub[4][1152];           // per-wave bf16 bias tile
    int b = blockIdx.z >> 1, split = blockIdx.z & 1;
    int h = blockIdx.y, grp = h >> 2;
    int qbase = blockIdx.x * 64;
    int tid = threadIdx.x, wid = tid >> 6, lane = tid & 63;
    int l16 = lane & 15, lq = lane >> 4;
    int kv_begin = split ? 576 : 0;
    int kv_end = split ? 1088 : 576;
    u16* bt = ub[wid];
    u16* Pw = P[wid];

    int rowbase = qbase + wid * 16;
    int qrow = rowbase + l16;
    short8 qa = *(const short8*)(qb + ((long)(b * 1088 + qrow)) * 512 + h * 32 + lq * 8);
    int irow[4];
#pragma unroll
    for (int r = 0; r < 4; r++) irow[r] = rowbase + lq * 4 + r;

    // staging sources: grp0=dist table (bf16), grp1=adj (f32), grp2=ehc (f32)
    bool stg = (grp <= 2);
    const u16* srcb = ebt + ((long)(b * 1024 + rowbase)) * 1024;
    const float* srcf = (grp == 1)
        ? adj + ((long)(b * 1024 + rowbase)) * 1024
        : ehc + (((long)(b * 4 + (h - 8))) * 1024 + rowbase) * 1024;
    int r8 = lane >> 3, c8 = lane & 7;       // bf16 staging coords (16B/lane)
    int row4 = lane >> 4, c16 = (lane & 15) * 4;  // f32 staging coords
    ushort8_t preb[2];
    floatx4 pref[4];

    float rsum[4] = {0.f, 0.f, 0.f, 0.f};
    floatx4 o[2] = {};
    floatx4 zacc = {0.f, 0.f, 0.f, 0.f};

    // initial stage
    if (stg) {
        if (grp == 0) {
#pragma unroll
            for (int p = 0; p < 2; p++)
                preb[p] = *(const ushort8_t*)(srcb + (long)(p * 8 + r8) * 1024 + kv_begin + c8 * 8);
#pragma unroll
            for (int p = 0; p < 2; p++)
                *(ushort8_t*)(bt + (p * 8 + r8) * 72 + c8 * 8) = preb[p];
        } else {
#pragma unroll
            for (int p = 0; p < 4; p++)
                pref[p] = *(const floatx4*)(srcf + (long)(p * 4 + row4) * 1024 + kv_begin + c16);
#pragma unroll
            for (int p = 0; p < 4; p++) {
                uint2_t w;
                w[0] = cvt_pk(pref[p][0], pref[p][1]);
                w[1] = cvt_pk(pref[p][2], pref[p][3]);
                *(uint2_t*)(bt + (p * 4 + row4) * 72 + c16) = w;
            }
        }
    }

    for (int kv = kv_begin; kv < kv_end; kv += 64) {
        // ---- S = Q K^T (Q pre-scaled by 1/sqrt(hd)) ----
        floatx4 sfr[4];
#pragma unroll
        for (int jf = 0; jf < 4; jf++) {
            int tok = kv + jf * 16 + l16;
            short8 kf = *(const short8*)(kb + ((long)(b * 1088 + tok)) * 512 + h * 32 + lq * 8);
            sfr[jf] = __builtin_amdgcn_mfma_f32_16x16x32_bf16(qa, kf, zacc, 0, 0, 0);
        }
        // prefetch next bias tile (issue early)
        int kvn = kv + 64;
        bool pf = stg && kvn < kv_end && kvn < 1024;
        if (pf) {
            if (grp == 0) {
#pragma unroll
                for (int p = 0; p < 2; p++)
                    preb[p] = *(const ushort8_t*)(srcb + (long)(p * 8 + r8) * 1024 + kvn + c8 * 8);
            } else {
#pragma unroll
                for (int p = 0; p < 4; p++)
                    pref[p] = *(const floatx4*)(srcf + (long)(p * 4 + row4) * 1024 + kvn + c16);
            }
        }
        // ---- bias + exp + P ----
#pragma unroll
        for (int r = 0; r < 4; r++) {
            float pv[4];
#pragma unroll
            for (int jf = 0; jf < 4; jf++) {
                int j = kv + jf * 16 + l16;
                float a = b2f(bt[(lq * 4 + r) * 72 + jf * 16 + l16]);
                if (j >= 1024) a = 0.f;
                float bias, scale;
                if (grp <= 1) { bias = 2.f * a - 1.f; scale = 0.25f + 0.75f * a; }
                else if (grp == 2) { bias = a; scale = 1.f; }
                else { bias = 0.f; scale = 1.f; }
                float p = __expf(sfr[jf][r] + bias) * scale;
                rsum[r] += p;
                pv[jf] = p;
            }
            u32 pk0 = cvt_pk(pv[0], pv[1]);
            u32 pk1 = cvt_pk(pv[2], pv[3]);
            u16* prow = Pw + (lq * 4 + r) * 72 + l16;
            prow[0] = (u16)pk0; prow[16] = (u16)(pk0 >> 16);
            prow[32] = (u16)pk1; prow[48] = (u16)(pk1 >> 16);
        }
        // ---- O += P V ----
#pragma unroll
        for (int s = 0; s < 2; s++) {
            short8 pa = *(const short8*)(Pw + l16 * 72 + s * 32 + lq * 8);
#pragma unroll
            for (int nf = 0; nf < 2; nf++) {
                const u16* vrow = vt + ((long)((b * 16 + h) * 32 + nf * 16 + l16)) * 1088
                                  + kv + s * 32 + lq * 8;
                short8 vf = *(const short8*)vrow;
                o[nf] = __builtin_amdgcn_mfma_f32_16x16x32_bf16(pa, vf, o[nf], 0, 0, 0);
            }
        }
        // write prefetched tile (late)
        if (pf) {
            if (grp == 0) {
#pragma unroll
                for (int p = 0; p < 2; p++)
                    *(ushort8_t*)(bt + (p * 8 + r8) * 72 + c8 * 8) = preb[p];
            } else {
#pragma unroll
                for (int p = 0; p < 4; p++) {
                    uint2_t w;
                    w[0] = cvt_pk(pref[p][0], pref[p][1]);
                    w[1] = cvt_pk(pref[p][2], pref[p][3]);
                    *(uint2_t*)(bt + (p * 4 + row4) * 72 + c16) = w;
                }
            }
        }
    }
    // deferred row-sum reduce (over l16 within each lq group)
#pragma unroll
    for (int r = 0; r < 4; r++) {
#pragma unroll
        for (int m = 1; m < 16; m <<= 1)
            rsum[r] += __shfl_xor(rsum[r], m, 64);
    }
    long pb = (((long)(split * 2 + b) * 16 + h) * 1024);
#pragma unroll
    for (int nf = 0; nf < 2; nf++)
#pragma unroll
        for (int r = 0; r < 4; r++)
            o_part[(pb + irow[r]) * 32 + nf * 16 + l16] = o[nf][r];
    if (l16 == 0) {
#pragma unroll
        for (int r = 0; r < 4; r++) l_part[pb + irow[r]] = rsum[r];
    }
}

// ---------------- attention combine (2 splits) ----------------
__global__ __launch_bounds__(256) void attn_combine(
    const float* __restrict__ o_part, const float* __restrict__ l_part,
    u16* __restrict__ att)
{
    int idx = blockIdx.x * 256 + threadIdx.x;     // 262144 total
    int c4 = idx & 7;
    int row = (idx >> 3) & 1023;
    int h = (idx >> 13) & 15;
    int b = (idx >> 17) & 1;
    long base = (((long)b * 16 + h) * 1024 + row) * 32 + c4 * 4;
    long lb0 = ((long)b * 16 + h) * 1024 + row;
    floatx4 a0 = *(const floatx4*)(o_part + base);
    floatx4 a1 = *(const floatx4*)(o_part + 1048576 + base);
    float inv = 1.f / (l_part[lb0] + l_part[32768 + lb0]);
    ushort4_t w;
#pragma unroll
    for (int e = 0; e < 4; e++) w[e] = f2b((a0[e] + a1[e]) * inv);
    *(ushort4_t*)(att + ((long)b * 1024 + row) * 512 + h * 32 + c4 * 4) = w;
}

// ---------------- Wo epilogue: residual + LN2 + out-init(h2+b2) ----------------
__global__ __launch_bounds__(256) void wo_ln2(
    const float* __restrict__ p0, const float* __restrict__ p1,
    const float* __restrict__ bo, const float* __restrict__ hidden,
    const float* __restrict__ g, const float* __restrict__ bta,
    const float* __restrict__ b2, float* __restrict__ out,
    u16* __restrict__ n2)
{
    int wid = threadIdx.x >> 6, lane = threadIdx.x & 63;
    int row = blockIdx.x * 4 + wid;
    long base = (long)row * 512 + lane * 8;
    float x[8];
#pragma unroll
    for (int hp = 0; hp < 2; hp++) {
        floatx4 a = *(const floatx4*)(hidden + base + hp * 4);
        floatx4 q0 = *(const floatx4*)(p0 + base + hp * 4);
        floatx4 q1 = *(const floatx4*)(p1 + base + hp * 4);
        floatx4 bb = *(const floatx4*)(bo + lane * 8 + hp * 4);
#pragma unroll
        for (int e = 0; e < 4; e++) x[hp * 4 + e] = a[e] + q0[e] + q1[e] + bb[e];
    }
    float s = 0.f, sq = 0.f;
#pragma unroll
    for (int j = 0; j < 8; j++) { s += x[j]; sq += x[j] * x[j]; }
#pragma unroll
    for (int m = 1; m < 64; m <<= 1) {
        s += __shfl_xor(s, m, 64);
        sq += __shfl_xor(sq, m, 64);
    }
    float mean = s * (1.f / 512.f);
    float var = sq * (1.f / 512.f) - mean * mean;
    float rstd = rsqrtf(var + 1e-5f);
    // out = h2 + b2 (FF2 atomics add gelu@W2 on top)
#pragma unroll
    for (int hp = 0; hp < 2; hp++) {
        floatx4 bb2 = *(const floatx4*)(b2 + lane * 8 + hp * 4);
        floatx4 w;
#pragma unroll
        for (int e = 0; e < 4; e++) w[e] = x[hp * 4 + e] + bb2[e];
        *(floatx4*)(out + base + hp * 4) = w;
    }
    const floatx4* gp = (const floatx4*)(g + lane * 8);
    const floatx4* bp = (const floatx4*)(bta + lane * 8);
    floatx4 g0 = gp[0], g1 = gp[1], bb0 = bp[0], bb1 = bp[1];
    float gg[8], bbv[8];
    gg[0] = g0[0]; gg[1] = g0[1]; gg[2] = g0[2]; gg[3] = g0[3];
    gg[4] = g1[0]; gg[5] = g1[1]; gg[6] = g1[2]; gg[7] = g1[3];
    bbv[0] = bb0[0]; bbv[1] = bb0[1]; bbv[2] = bb0[2]; bbv[3] = bb0[3];
    bbv[4] = bb1[0]; bbv[5] = bb1[1]; bbv[6] = bb1[2]; bbv[7] = bb1[3];
    ushort8_t ov;
#pragma unroll
    for (int j = 0; j < 8; j++) ov[j] = f2b((x[j] - mean) * rstd * gg[j] + bbv[j]);
    *(ushort8_t*)(n2 + base) = ov;
}

// ---------------- launch ----------------
extern "C" void kernel_launch(void* const* d_in, const int* in_sizes, int n_in,
                              void* d_out, int out_size, void* d_ws, size_t ws_size,
                              hipStream_t stream) {
    const float* hidden = (const float*)d_in[0];
    const float* adjacency = (const float*)d_in[1];
    const float* positions = (const float*)d_in[2];
    const float* context = (const float*)d_in[3];
    const float* ehc = (const float*)d_in[4];
    const float* Wq = (const float*)d_in[5];
    const float* bq = (const float*)d_in[6];
    const float* Wk = (const float*)d_in[7];
    const float* bk = (const float*)d_in[8];
    const float* Wv = (const float*)d_in[9];
    const float* bv = (const float*)d_in[10];
    const float* Wo = (const float*)d_in[11];
    const float* bo = (const float*)d_in[12];
    const float* ln1g = (const float*)d_in[13];
    const float* ln1b = (const float*)d_in[14];
    const float* ln2g = (const float*)d_in[15];
    const float* ln2b = (const float*)d_in[16];
    const float* W1 = (const float*)d_in[17];
    const float* b1 = (const float*)d_in[18];
    const float* W2 = (const float*)d_in[19];
    const float* b2 = (const float*)d_in[20];
    float* out = (float*)d_out;

    char* ws = (char*)d_ws;
    u16* wqkv_b = (u16*)(ws + 0);                 // [1536][512] bf16
    u16* wo_b   = (u16*)(ws + 1572864);
    u16* w1_b   = (u16*)(ws + 2097152);
    u16* w2_b   = (u16*)(ws + 4194304);
    u16* ks_b   = (u16*)(ws + 6291456);           // [2][1088][512]
    u16* q_b    = (u16*)(ws + 8519680);           // [2][1088][512] (pre-scaled)
    u16* k_b    = (u16*)(ws + 10747904);          // [2][1088][512]
    u16* vt_b   = (u16*)(ws + 12976128);          // [2][16][32][1088]
    u16* att_b  = (u16*)(ws + 15204352);          // [2][1024][512]
    u16* n2_b   = (u16*)(ws + 17301504);          // [2048][512]
    u16* g_b    = (u16*)(ws + 19398656);          // [2048][2048] (ends 27787264)
    float* o_part = (float*)(ws + 27787264);      // [2split][2][16][1024][32] f32 (8.4MB)
    float* l_part = (float*)(ws + 36175872);      // [2split][2][16][1024] f32
    float* wo_p  = (float*)(ws + 36438016);       // [2][2048][512] f32 (8.4MB)
    u16* ebt_b   = (u16*)(ws + 44826624);         // [2][1024][1024] bf16 (4.2MB, end ~49MB)

    cvt_ln<<<5664, 256, 0, stream>>>(Wq, Wk, Wv, Wo, W1, W2,
                                     wqkv_b, wqkv_b + 262144, wqkv_b + 524288,
                                     wo_b, w1_b, w2_b,
                                     hidden, context, ln1g, ln1b, ks_b,
                                     positions, ebt_b);
    gemm_big<0, 3><<<dim3(12, 17), 256, 0, stream>>>(
        ks_b, wqkv_b, bq, bk, bv, q_b, k_b, vt_b, 2176, 1536, 512);
    attn_kernel<<<dim3(16, 16, 4), 256, 0, stream>>>(
        q_b, k_b, vt_b, adjacency, ehc, ebt_b, o_part, l_part);
    attn_combine<<<1024, 256, 0, stream>>>(o_part, l_part, att_b);
    gemm_sk<4><<<dim3(4, 32, 2), 256, 0, stream>>>(
        att_b, wo_b, wo_p, 2048, 512, 512, 256);
    wo_ln2<<<512, 256, 0, stream>>>(wo_p, wo_p + 1048576, bo, hidden,
                                    ln2g, ln2b, b2, out, n2_b);
    gemm_big<1, 1><<<dim3(16, 16), 256, 0, stream>>>(
        n2_b, w1_b, b1, nullptr, nullptr, g_b, nullptr, nullptr, 2048, 2048, 512);
    gemm_sk<5><<<dim3(4, 32, 4), 256, 0, stream>>>(
        g_b, w2_b, out, 2048, 512, 2048, 512);
}